// Round 9
// baseline (1474.850 us; speedup 1.0000x reference)
//
#include <hip/hip_runtime.h>
#include <hip/hip_fp16.h>
#include <math.h>

// ============================================================================
// ConflictNet: 30-step graph-PDE scan, B=2, N=8000, DY=12.
// Round 16 (= R15 resubmit; R15 bench was an infra failure, no signal).
// Base = R12 split (1241us verified). k_mlp restructured from
// 2 passes x 2 nodes to ONE pass x 4 nodes per wave: the per-lane-distinct
// WEIGHT ds_read_b128s (63/lane/sweep, the LDS-BW-bound part; activation
// reads are same-address broadcasts) are paid once instead of twice.
// Per-node fma order identical -> bit-exact vs R12 (absmax 0.25).
// LDS 45.2KB pack + 32x864B act slots = 72.8KB -> still 2 blocks/CU.
// k_gather unchanged (8B packed {f, half2(ax,ay)} payload).
// ============================================================================

namespace {
constexpr int NB = 2;
constexpr int NN = 8000;
constexpr int BN = NB * NN;   // 16000
constexpr int TS = 30;
constexpr int CAP = 64;

// ---- packed weight layout (ws staging area and LDS) ----
constexpr int P_T0 = 0;        // [6][64][4]  Wt0 rows 0-23   (1536)
constexpr int P_Q0 = 1536;     // [6][64][4]  Wq0 rows 0-23   (1536)
constexpr int P_W1 = 3072;     // [16][64][4] Wt1|Wq1 fused   (4096)
constexpr int P_Q2 = 7168;     // [8][12][4]  Wq2             (384)
constexpr int P_Z  = 7552;     // [32]        Wt2[:,25]       (32)
constexpr int P_D0 = 7584;     // [3][32][4]  Wd0 rows 0-11   (384)
constexpr int P_D1 = 7968;     // [8][32][4]  Wd1             (1024)
constexpr int P_D2 = 8992;     // [8][64][4]  Wd2             (2048)
constexpr int P_D3 = 11040;    // [64]        Wd3             (64)
constexpr int P_BT1 = 11104;   // [32] bt1
constexpr int P_BQ1 = 11136;   // [32] bq1
constexpr int P_BQ2 = 11168;   // [16] bq2 (12 used)
constexpr int P_BD1 = 11184;   // [32] bd1
constexpr int P_BD2 = 11216;   // [64] bd2
constexpr int P_MISC= 11280;   // [0]=bd3[0], [1]=bt2[25]
constexpr int PACK_N = 11296;  // 45.2 KB

// ---- per-node activation slot in LDS (floats) ----
constexpr int A_AG = 0;
constexpr int A_NV = 0;
constexpr int A_H1 = 24;
constexpr int A_D1 = 24;
constexpr int A_D2 = 56;
constexpr int A_H2 = 152;
constexpr int A_SLOT = 216;    // 864 B
// 32 slots/block (8 waves x 4 nodes): LDS total = 45.2 + 27.6 = 72.8 KB

// ---- workspace float offsets ----
constexpr int O_COEFF = 0;                 // 144
constexpr int O_CFT   = 144;               // 144
constexpr int O_DIJ   = 288;               // 12
constexpr int O_MUIJ  = 300;               // 12
constexpr int O_MC    = 312;               // 12
constexpr int O_PACK  = 336;               // PACK_N
constexpr int O_GPX   = O_PACK + PACK_N + 16;  // BN
constexpr int O_GPY   = O_GPX + BN;
constexpr int O_H1T   = O_GPY + BN;        // BN*64
constexpr int O_H1Q   = O_H1T + BN*64;     // BN*64
constexpr int O_H1D   = O_H1Q + BN*64;     // BN*32
constexpr int O_FEATA = O_H1D + BN*32;     // BN*12
constexpr int O_FEATB = O_FEATA + BN*12;
constexpr int O_AXY2A = O_FEATB + BN*12;   // BN*12 float2 = BN*24 floats
constexpr int O_AXY2B = O_AXY2A + BN*24;
constexpr int O_ACT   = O_AXY2B + BN*24;   // [BN][48]: 0-11 agw, 12-23 udiff, 24-35 urig
constexpr int O_FLTEND= O_ACT + BN*48;
// int region: rev counts [BN], rev entries [BN*CAP]
constexpr int O_STG   = O_FLTEND + BN + BN*CAP;   // q0 staging [TS][BN*12]
constexpr int STG_N = TS*BN*12;
constexpr size_t WS_NEED = (size_t)(O_STG + STG_N) * 4;

// ---- output flat offsets ----
constexpr int OUS  = 0;
constexpr int OMIX = BN*TS;
constexpr int OQ0  = 2*BN*TS;
constexpr int OFD  = OQ0 + BN*12*TS;
}

__device__ __forceinline__ float group5_sum(float v, int lane) {
  int g = lane / 12, c = lane % 12;
  float s1 = __shfl(v, c + 12*((g+1)%5));
  float s2 = __shfl(v, c + 12*((g+2)%5));
  float s3 = __shfl(v, c + 12*((g+3)%5));
  float s4 = __shfl(v, c + 12*((g+4)%5));
  return v + s1 + s2 + s3 + s4;
}

__device__ __forceinline__ float pack_axy(float a, float b) {
  union { __half2 h2; float f; } cv;
  cv.h2 = __floats2half2_rn(a, b);
  return cv.f;
}
__device__ __forceinline__ void unpack_axy(float p, float& a, float& b) {
  union { float f; __half2 h2; } cv;
  cv.f = p;
  a = __low2float(cv.h2);
  b = __high2float(cv.h2);
}

// ---------------------------------------------------------------------------
__global__ void k_setup_small(const float* __restrict__ D, const float* __restrict__ mu,
                              const float* __restrict__ cv, float* ws) {
  int t = threadIdx.x;
  for (int e = t; e < 144; e += 256) {
    int r = e / 12, q = e % 12;
    int rb = r >> 2, cb = q >> 2, ri = r & 3, qi = q & 3;
    float val = 0.f;
    if (rb == cb) {
      int f = ri*4 + qi;
      if (f % 5 == 0) val = 1.f;
      else val = cv[64 + rb*12 + (f/5)*4 + (f%5) - 1];
    } else if (rb == 0 && cb == 2) val = cv[     ri*4 + qi];
    else if   (rb == 1 && cb == 2) val = cv[16 + ri*4 + qi];
    else if   (rb == 2 && cb == 0) val = cv[32 + ri*4 + qi];
    else if   (rb == 2 && cb == 1) val = cv[48 + ri*4 + qi];
    ws[O_COEFF + e] = fmaxf(val, 0.f);
  }
  if (t < 12) {
    ws[O_DIJ + t]  = (t < 4) ? 0.f : fmaxf(D[t-4], 0.f);
    ws[O_MUIJ + t] = (t < 4) ? fmaxf(mu[t], 0.f) : ((t < 8) ? 0.f : fmaxf(mu[t-4], 0.f));
  }
  __syncthreads();
  if (t < 144) {
    int r = t / 12, c = t % 12;
    ws[O_CFT + c*12 + r] = ws[O_COEFF + t];
  }
  if (t < 12) {
    float acc = 0.f;
    for (int c = 0; c < 12; c++) acc += ws[O_MUIJ + c] * ws[O_COEFF + c*12 + t];
    ws[O_MC + t] = acc;
  }
}

// ---------------------------------------------------------------------------
__global__ void k_xpose(const float* __restrict__ Wt0, const float* __restrict__ Wq0,
                        const float* __restrict__ Wt1, const float* __restrict__ Wq1,
                        const float* __restrict__ Wt2, const float* __restrict__ Wq2,
                        const float* __restrict__ Wd0, const float* __restrict__ Wd1,
                        const float* __restrict__ Wd2, const float* __restrict__ Wd3,
                        const float* __restrict__ bt1, const float* __restrict__ bq1,
                        const float* __restrict__ bt2, const float* __restrict__ bq2,
                        const float* __restrict__ bd1, const float* __restrict__ bd2,
                        const float* __restrict__ bd3,
                        float* ws) {
  const int t = blockIdx.x * blockDim.x + threadIdx.x;
  const int G = gridDim.x * blockDim.x;
  float* P = ws + O_PACK;
  for (int e = t; e < 1536; e += G) {
    int q = e / 256, r = e % 256, l = r / 4, j = r % 4;
    P[P_T0 + e] = Wt0[(4*q+j)*64 + l];
    P[P_Q0 + e] = Wq0[(4*q+j)*64 + l];
  }
  for (int e = t; e < 4096; e += G) {
    int q = e / 256, r = e % 256, l = r / 4, j = r % 4;
    P[P_W1 + e] = (l < 32) ? Wt1[(4*q+j)*32 + l] : Wq1[(4*q+j)*32 + (l-32)];
  }
  for (int e = t; e < 384; e += G) {
    int q = e / 48, r = e % 48, c = r / 4, j = r % 4;
    P[P_Q2 + e] = Wq2[(4*q+j)*12 + c];
  }
  for (int e = t; e < 32; e += G) P[P_Z + e] = Wt2[e*26 + 25];
  for (int e = t; e < 384; e += G) {
    int q = e / 128, r = e % 128, l = r / 4, j = r % 4;
    P[P_D0 + e] = Wd0[(4*q+j)*32 + l];
  }
  for (int e = t; e < 1024; e += G) {
    int q = e / 128, r = e % 128, l = r / 4, j = r % 4;
    P[P_D1 + e] = Wd1[(4*q+j)*32 + l];
  }
  for (int e = t; e < 2048; e += G) {
    int q = e / 256, r = e % 256, l = r / 4, j = r % 4;
    P[P_D2 + e] = Wd2[(4*q+j)*64 + l];
  }
  for (int e = t; e < 64; e += G) P[P_D3 + e] = Wd3[e];
  for (int e = t; e < 32; e += G) {
    P[P_BT1 + e] = bt1[e];
    P[P_BQ1 + e] = bq1[e];
    P[P_BD1 + e] = bd1[e];
  }
  for (int e = t; e < 12; e += G) P[P_BQ2 + e] = bq2[e];
  for (int e = t; e < 64; e += G) P[P_BD2 + e] = bd2[e];
  if (t == 0) { P[P_MISC + 0] = bd3[0]; P[P_MISC + 1] = bt2[25]; }
}

// ---------------------------------------------------------------------------
__global__ __launch_bounds__(256) void k_setup_node(
    const float* __restrict__ phi, const float* __restrict__ feat_dy,
    const float* __restrict__ feat_st,
    const int* __restrict__ adj4, const int* __restrict__ adj25,
    const float* __restrict__ Wt0, const float* __restrict__ bt0,
    const float* __restrict__ Wq0, const float* __restrict__ bq0,
    const float* __restrict__ Wd0, const float* __restrict__ bd0,
    float* ws, int* wsi) {
  const int wid  = (blockIdx.x * blockDim.x + threadIdx.x) >> 6;
  const int lane = threadIdx.x & 63;
  if (wid >= BN) return;
  const int b = wid / NN, n = wid % NN;

  const int* a4 = adj4 + n*4;
  const float gpx = phi[b*NN + a4[1]] - phi[b*NN + a4[0]];
  const float gpy = phi[b*NN + a4[3]] - phi[b*NN + a4[2]];
  if (lane == 0) { ws[O_GPX + wid] = gpx; ws[O_GPY + wid] = gpy; wsi[wid] = 0; }

  int idx = 0; float w = 0.f;
  if (lane < 25) { idx = adj25[n*25 + lane]; w = (lane == 0) ? 1.f : 0.01f; }
  float phiw = (lane < 25) ? w * phi[b*NN + idx] : 0.f;
  #pragma unroll
  for (int s = 32; s > 0; s >>= 1) phiw += __shfl_xor(phiw, s);

  float stv[6], stw[6];
  #pragma unroll
  for (int j = 0; j < 6; j++) {
    float x = (lane < 25) ? w * feat_st[(b*NN + idx)*6 + j] : 0.f;
    #pragma unroll
    for (int s = 32; s > 0; s >>= 1) x += __shfl_xor(x, s);
    stw[j] = x;
    stv[j] = feat_st[(b*NN + n)*6 + j];
  }
  const float phiv = phi[b*NN + n];

  float hT = bt0[lane] + phiv*Wt0[24*64 + lane] + phiw*Wt0[25*64 + lane];
  float hQ = bq0[lane] + phiv*Wq0[24*64 + lane] + phiw*Wq0[25*64 + lane];
  #pragma unroll
  for (int i = 0; i < 12; i++) {
    hT = fmaf(ws[O_DIJ  + i], Wt0[(26+i)*64 + lane], hT);
    hT = fmaf(ws[O_MUIJ + i], Wt0[(38+i)*64 + lane], hT);
  }
  #pragma unroll
  for (int j = 0; j < 6; j++) {
    hT = fmaf(stv[j], Wt0[(50+j)*64 + lane], hT);
    hT = fmaf(stw[j], Wt0[(56+j)*64 + lane], hT);
    hQ = fmaf(stv[j], Wq0[(26+j)*64 + lane], hQ);
    hQ = fmaf(stw[j], Wq0[(32+j)*64 + lane], hQ);
  }
  ws[O_H1T + wid*64 + lane] = hT;
  ws[O_H1Q + wid*64 + lane] = hQ;
  if (lane < 32) {
    float hD = bd0[lane];
    #pragma unroll
    for (int j = 0; j < 6; j++) hD = fmaf(stv[j], Wd0[(12+j)*32 + lane], hD);
    ws[O_H1D + wid*32 + lane] = hD;
  }
  if (lane < 12) {
    float f = feat_dy[wid*12 + lane];
    ws[O_FEATA + wid*12 + lane] = f;
    float mass = (f == 0.f) ? 1.f : f;
    float mc = ws[O_MC + lane];
    float axv = fminf(fmaxf(gpx*mc/mass, -2.f), 2.f);
    float ayv = fminf(fmaxf(gpy*mc/mass, -2.f), 2.f);
    float2* a2a = (float2*)(ws + O_AXY2A);
    a2a[wid*12 + lane] = make_float2(f, pack_axy(axv, ayv));
  }
}

// ---------------------------------------------------------------------------
__global__ void k_build_rev(const int* __restrict__ adj25, int* wsi) {
  int i = blockIdx.x * blockDim.x + threadIdx.x;
  if (i >= BN * 25) return;
  int b = i / (NN * 25);
  int rem = i % (NN * 25);
  int m = rem / 25, k = rem % 25;
  int tgt = adj25[i];
  int slot = atomicAdd(&wsi[b*NN + tgt], 1);
  if (slot < CAP) wsi[BN + (b*NN + tgt)*CAP + slot] = (m << 5) | k;
}

// ---------------------------------------------------------------------------
// Gather kernel (unchanged from R12): one node per wave, no LDS, one-round
// index loads + shfl redistribution; u_rig on 8B packed {f, half2(ax,ay)}.
// ---------------------------------------------------------------------------
__global__ __launch_bounds__(512) void k_gather(
    const float* __restrict__ ws,
    const int* __restrict__ rcnt, const int* __restrict__ rent,
    const float* __restrict__ fsrc, const float2* __restrict__ a2src,
    const int* __restrict__ adj4, const int* __restrict__ adj25,
    float* __restrict__ actb) {
  const int wid_raw = (int)((blockIdx.x * blockDim.x + threadIdx.x) >> 6);
  if (wid_raw >= BN) return;
  const int wid  = __builtin_amdgcn_readfirstlane(wid_raw);  // wave-uniform
  const int lane = threadIdx.x & 63;
  const int c12  = lane % 12;
  const int g    = lane / 12;
  const int b = wid / NN, n = wid % NN;

  const int* a4p = adj4 + n*4;                       // uniform -> s_load
  const int m0 = a4p[0], m1 = a4p[1], m2 = a4p[2], m3 = a4p[3];
  int cnt = rcnt[wid]; if (cnt > CAP) cnt = CAP;     // uniform -> s_load
  const int idxv = (lane < 25) ? adj25[n*25 + lane] : 0;
  const int pkv  = rent[wid*CAP + lane];
  const float f_c  = fsrc[wid*12 + c12];
  const float dij  = ws[O_DIJ  + c12];
  const float muij = ws[O_MUIJ + c12];
  const float4* CFTp = (const float4*)(ws + O_CFT + c12*12);
  const float4 cf0 = CFTp[0], cf1 = CFTp[1], cf2 = CFTp[2];

  float agw = 0.f;
  {
    const int i0 = __shfl(idxv, g);
    const int i1 = __shfl(idxv, g + 5);
    const int i2 = __shfl(idxv, g + 10);
    const int i3 = __shfl(idxv, g + 15);
    const int i4 = __shfl(idxv, g + 20);
    if (g < 5) {
      const float v0 = fsrc[(b*NN + i0)*12 + c12];
      const float v1 = fsrc[(b*NN + i1)*12 + c12];
      const float v2 = fsrc[(b*NN + i2)*12 + c12];
      const float v3 = fsrc[(b*NN + i3)*12 + c12];
      const float v4 = fsrc[(b*NN + i4)*12 + c12];
      const float w0 = (g == 0) ? 1.f : 0.01f;
      agw = fmaf(w0,    v0, agw);
      agw = fmaf(0.01f, v1, agw);
      agw = fmaf(0.01f, v2, agw);
      agw = fmaf(0.01f, v3, agw);
      agw = fmaf(0.01f, v4, agw);
    }
    agw = group5_sum(agw, lane);
  }

  float udiff;
  {
    const float f0 = fsrc[(b*NN+m0)*12 + c12];
    const float f1 = fsrc[(b*NN+m1)*12 + c12];
    const float f2 = fsrc[(b*NN+m2)*12 + c12];
    const float f3 = fsrc[(b*NN+m3)*12 + c12];
    const float gx0 = ws[O_GPX + b*NN + m0], gx1 = ws[O_GPX + b*NN + m1];
    const float gy2 = ws[O_GPY + b*NN + m2], gy3 = ws[O_GPY + b*NN + m3];
    const float J = 4.f * ((f0+f1+f2+f3) - 4.f*f_c);
    const float Fdiv = gx1*f1 - gx0*f0 + gy3*f3 - gy2*f2;
    const float v = dij*J - muij*Fdiv;
    float acc;
    acc  = __shfl(v, 0) * cf0.x;
    acc  = fmaf(__shfl(v, 1), cf0.y, acc);
    acc  = fmaf(__shfl(v, 2), cf0.z, acc);
    acc  = fmaf(__shfl(v, 3), cf0.w, acc);
    acc  = fmaf(__shfl(v, 4), cf1.x, acc);
    acc  = fmaf(__shfl(v, 5), cf1.y, acc);
    acc  = fmaf(__shfl(v, 6), cf1.z, acc);
    acc  = fmaf(__shfl(v, 7), cf1.w, acc);
    acc  = fmaf(__shfl(v, 8), cf2.x, acc);
    acc  = fmaf(__shfl(v, 9), cf2.y, acc);
    acc  = fmaf(__shfl(v,10), cf2.z, acc);
    acc  = fmaf(__shfl(v,11), cf2.w, acc);
    udiff = acc;
  }

  float urig;
  {
    float usc = 0.f;
    #pragma unroll
    for (int it = 0; it < 8; ++it) {
      const int e = g + 5*it;
      const bool val = (g < 5) && (e < cnt);
      const int pk = __shfl(pkv, e & 63);
      const int m = pk >> 5, k = pk & 31;
      const int off = val ? ((b*NN + m)*12 + c12) : (wid*12 + c12);
      const float2 sm = a2src[off];
      float ax, ay; unpack_axy(sm.y, ax, ay);
      const float kx = (float)(k - (k/5)*5);
      const float ky = (float)(k/5);
      const float px = fmaxf(1.f - fabsf(ax - kx), 0.f);
      const float py = fmaxf(1.f - fabsf(ay - ky), 0.f);
      usc = fmaf(val ? px*py : 0.f, sm.x, usc);
    }
    if (cnt > 40) {            // uniform branch, ~0.2% of nodes
      #pragma unroll
      for (int it = 8; it < 13; ++it) {
        const int e = g + 5*it;
        const bool val = (g < 5) && (e < cnt);
        const int pk = __shfl(pkv, e & 63);
        const int m = pk >> 5, k = pk & 31;
        const int off = val ? ((b*NN + m)*12 + c12) : (wid*12 + c12);
        const float2 sm = a2src[off];
        float ax, ay; unpack_axy(sm.y, ax, ay);
        const float kx = (float)(k - (k/5)*5);
        const float ky = (float)(k/5);
        const float px = fmaxf(1.f - fabsf(ax - kx), 0.f);
        const float py = fmaxf(1.f - fabsf(ay - ky), 0.f);
        usc = fmaf(val ? px*py : 0.f, sm.x, usc);
      }
    }
    usc = group5_sum(usc, lane);
    urig = usc - f_c;
  }

  const float ov = (lane < 12) ? agw : ((lane < 24) ? udiff : urig);
  if (lane < 36) actb[wid*48 + lane] = ov;
}

// ---------------------------------------------------------------------------
// MLP kernel: 512 threads = 8 waves; ONE pass of 4 nodes per wave.
// Weight ds_read_b128s (per-lane-distinct, LDS-BW-bound) are read once per
// wave instead of twice; activation reads are same-address broadcasts.
// ---------------------------------------------------------------------------
__global__ __launch_bounds__(512) void k_mlp(
    const float* __restrict__ ws, const float* __restrict__ actb, int t,
    const float* __restrict__ fsrc,
    float* __restrict__ fdst, float2* __restrict__ a2dst,
    float* __restrict__ stg, int use_stage,
    float* __restrict__ out) {
  __shared__ __attribute__((aligned(16))) float sh[PACK_N + 32*A_SLOT];
  const int tid = threadIdx.x;
  {
    const float4* wp = (const float4*)(ws + O_PACK);
    float4* sp = (float4*)sh;
    for (int e = tid; e < PACK_N/4; e += 512) sp[e] = wp[e];
  }
  __syncthreads();

  const int wv   = tid >> 6;
  const int wvq  = __builtin_amdgcn_readfirstlane(wv);  // uniform wave id
  const int lane = tid & 63;
  const int c12 = lane % 12;
  const int l32 = lane & 31;
  const bool isQ = lane >= 32;
  float* actB = sh + PACK_N + wvq*4*A_SLOT;   // 4 slots per wave

  const float mcv = ws[O_MC + c12];
  const int nb = (blockIdx.x*8 + wvq) * 4;    // uniform: 4 nodes per wave

  float f_c[4], udiff[4], urig[4];
  #pragma unroll
  for (int j = 0; j < 4; j++) {
    const int wid = nb + j;
    float* actj = actB + j*A_SLOT;
    f_c[j] = fsrc[wid*12 + c12];
    const float agv = actb[wid*48 + c12];
    udiff[j] = actb[wid*48 + 12 + c12];
    urig[j]  = actb[wid*48 + 24 + c12];
    if (lane < 24) actj[A_AG + lane] = (lane < 12) ? f_c[j] : agv;
  }

  // ---- h1 ----
  {
    float h1t[4], h1q[4];
    #pragma unroll
    for (int j = 0; j < 4; j++) {
      h1t[j] = ws[O_H1T + (nb+j)*64 + lane];
      h1q[j] = ws[O_H1Q + (nb+j)*64 + lane];
    }
    #pragma unroll
    for (int q = 0; q < 6; q++) {
      const float4 wt = *(const float4*)&sh[P_T0 + q*256 + lane*4];
      const float4 wq = *(const float4*)&sh[P_Q0 + q*256 + lane*4];
      #pragma unroll
      for (int j = 0; j < 4; j++) {
        const float4 a = *(const float4*)&actB[j*A_SLOT + A_AG + 4*q];
        h1t[j] = fmaf(a.x, wt.x, h1t[j]); h1q[j] = fmaf(a.x, wq.x, h1q[j]);
        h1t[j] = fmaf(a.y, wt.y, h1t[j]); h1q[j] = fmaf(a.y, wq.y, h1q[j]);
        h1t[j] = fmaf(a.z, wt.z, h1t[j]); h1q[j] = fmaf(a.z, wq.z, h1q[j]);
        h1t[j] = fmaf(a.w, wt.w, h1t[j]); h1q[j] = fmaf(a.w, wq.w, h1q[j]);
      }
    }
    #pragma unroll
    for (int j = 0; j < 4; j++) {
      actB[j*A_SLOT + A_H1 + lane]      = fmaxf(h1t[j], 0.f);
      actB[j*A_SLOT + A_H1 + 64 + lane] = fmaxf(h1q[j], 0.f);
    }
  }

  // ---- h2 ----
  {
    const int hoff = isQ ? 64 : 0;
    float h2[4];
    const float bias = isQ ? sh[P_BQ1 + l32] : sh[P_BT1 + l32];
    #pragma unroll
    for (int j = 0; j < 4; j++) h2[j] = bias;
    #pragma unroll
    for (int q = 0; q < 16; q++) {
      const float4 w = *(const float4*)&sh[P_W1 + q*256 + lane*4];
      #pragma unroll
      for (int j = 0; j < 4; j++) {
        const float4 a = *(const float4*)&actB[j*A_SLOT + A_H1 + hoff + 4*q];
        h2[j] = fmaf(a.x, w.x, h2[j]);
        h2[j] = fmaf(a.y, w.y, h2[j]);
        h2[j] = fmaf(a.z, w.z, h2[j]);
        h2[j] = fmaf(a.w, w.w, h2[j]);
      }
    }
    #pragma unroll
    for (int j = 0; j < 4; j++) actB[j*A_SLOT + A_H2 + lane] = fmaxf(h2[j], 0.f);
  }

  // ---- mix + q0 ----
  float mix[4], q0v[4];
  {
    float mz[4], q0[4];
    #pragma unroll
    for (int j = 0; j < 4; j++) { mz[j] = sh[P_MISC + 1]; q0[j] = sh[P_BQ2 + c12]; }
    #pragma unroll
    for (int q = 0; q < 8; q++) {
      const float4 wz = *(const float4*)&sh[P_Z + 4*q];
      const float4 wq = *(const float4*)&sh[P_Q2 + q*48 + c12*4];
      #pragma unroll
      for (int j = 0; j < 4; j++) {
        const float4 at = *(const float4*)&actB[j*A_SLOT + A_H2 + 4*q];
        const float4 aq = *(const float4*)&actB[j*A_SLOT + A_H2 + 32 + 4*q];
        mz[j] = fmaf(at.x, wz.x, mz[j]); q0[j] = fmaf(aq.x, wq.x, q0[j]);
        mz[j] = fmaf(at.y, wz.y, mz[j]); q0[j] = fmaf(aq.y, wq.y, q0[j]);
        mz[j] = fmaf(at.z, wz.z, mz[j]); q0[j] = fmaf(aq.z, wq.z, q0[j]);
        mz[j] = fmaf(at.w, wz.w, mz[j]); q0[j] = fmaf(aq.w, wq.w, q0[j]);
      }
    }
    #pragma unroll
    for (int j = 0; j < 4; j++) {
      mix[j] = 1.f / (1.f + expf(-mz[j]));
      q0v[j] = q0[j];
    }
  }

  // ---- update + outputs + next {f, packed ax/ay} ----
  #pragma unroll
  for (int j = 0; j < 4; j++) {
    const int wid = nb + j;
    float* actj = actB + j*A_SLOT;
    const float newv = f_c[j] + mix[j]*udiff[j] + (1.f - mix[j])*urig[j] + q0v[j];
    if (lane < 12) {
      actj[A_NV + lane] = newv;
      if (use_stage) stg[(size_t)t*BN*12 + wid*12 + lane] = q0v[j];
      else           out[OQ0 + (wid*12 + lane)*TS + t] = q0v[j];
      out[OFD + (wid*TS + t)*12 + lane] = newv;
      fdst[wid*12 + lane] = newv;
      float mass = (newv == 0.f) ? 1.f : newv;
      float gpxn = ws[O_GPX + wid], gpyn = ws[O_GPY + wid];
      float axn = fminf(fmaxf(gpxn*mcv/mass, -2.f), 2.f);
      float ayn = fminf(fmaxf(gpyn*mcv/mass, -2.f), 2.f);
      a2dst[wid*12 + lane] = make_float2(newv, pack_axy(axn, ayn));
    }
    if (lane == 0) out[OMIX + wid*TS + t] = mix[j];
  }

  // ---- dec d1 ----
  {
    float d1[4];
    #pragma unroll
    for (int j = 0; j < 4; j++) d1[j] = ws[O_H1D + (nb+j)*32 + l32];
    #pragma unroll
    for (int q = 0; q < 3; q++) {
      const float4 w = *(const float4*)&sh[P_D0 + q*128 + l32*4];
      #pragma unroll
      for (int j = 0; j < 4; j++) {
        const float4 a = *(const float4*)&actB[j*A_SLOT + A_NV + 4*q];
        d1[j] = fmaf(a.x, w.x, d1[j]);
        d1[j] = fmaf(a.y, w.y, d1[j]);
        d1[j] = fmaf(a.z, w.z, d1[j]);
        d1[j] = fmaf(a.w, w.w, d1[j]);
      }
    }
    if (lane < 32) {
      #pragma unroll
      for (int j = 0; j < 4; j++) actB[j*A_SLOT + A_D1 + lane] = fmaxf(d1[j], 0.f);
    }
  }
  // ---- dec d2 ----
  {
    float d2[4];
    const float bias = sh[P_BD1 + l32];
    #pragma unroll
    for (int j = 0; j < 4; j++) d2[j] = bias;
    #pragma unroll
    for (int q = 0; q < 8; q++) {
      const float4 w = *(const float4*)&sh[P_D1 + q*128 + l32*4];
      #pragma unroll
      for (int j = 0; j < 4; j++) {
        const float4 a = *(const float4*)&actB[j*A_SLOT + A_D1 + 4*q];
        d2[j] = fmaf(a.x, w.x, d2[j]);
        d2[j] = fmaf(a.y, w.y, d2[j]);
        d2[j] = fmaf(a.z, w.z, d2[j]);
        d2[j] = fmaf(a.w, w.w, d2[j]);
      }
    }
    if (lane < 32) {
      #pragma unroll
      for (int j = 0; j < 4; j++) actB[j*A_SLOT + A_D2 + lane] = fmaxf(d2[j], 0.f);
    }
  }
  // ---- dec d3 + wave reduce ----
  {
    float d3[4];
    const float bias = sh[P_BD2 + lane];
    #pragma unroll
    for (int j = 0; j < 4; j++) d3[j] = bias;
    #pragma unroll
    for (int q = 0; q < 8; q++) {
      const float4 w = *(const float4*)&sh[P_D2 + q*256 + lane*4];
      #pragma unroll
      for (int j = 0; j < 4; j++) {
        const float4 a = *(const float4*)&actB[j*A_SLOT + A_D2 + 4*q];
        d3[j] = fmaf(a.x, w.x, d3[j]);
        d3[j] = fmaf(a.y, w.y, d3[j]);
        d3[j] = fmaf(a.z, w.z, d3[j]);
        d3[j] = fmaf(a.w, w.w, d3[j]);
      }
    }
    const float wd3 = sh[P_D3 + lane];
    float u[4];
    #pragma unroll
    for (int j = 0; j < 4; j++) u[j] = fmaxf(d3[j], 0.f) * wd3;
    #pragma unroll
    for (int s2 = 32; s2 > 0; s2 >>= 1) {
      #pragma unroll
      for (int j = 0; j < 4; j++) u[j] += __shfl_xor(u[j], s2);
    }
    if (lane == 0) {
      const float b3 = sh[P_MISC + 0];
      #pragma unroll
      for (int j = 0; j < 4; j++) out[OUS + (nb+j)*TS + t] = u[j] + b3;
    }
  }
}

// ---------------------------------------------------------------------------
// Final reorder: staged step-major q0 -> (B,N,12,1,T) layout.
// ---------------------------------------------------------------------------
__global__ void k_out(const float* __restrict__ stg, float* __restrict__ out) {
  const size_t NQ = (size_t)BN*12*TS;
  size_t i = (size_t)blockIdx.x * blockDim.x + threadIdx.x;
  if (i < NQ) {
    int e = (int)(i / TS), t = (int)(i % TS);
    out[OQ0 + i] = stg[(size_t)t*BN*12 + e];
  }
}

// ---------------------------------------------------------------------------
extern "C" void kernel_launch(void* const* d_in, const int* in_sizes, int n_in,
                              void* d_out, int out_size, void* d_ws, size_t ws_size,
                              hipStream_t stream) {
  const float* phi     = (const float*)d_in[0];
  const float* feat_dy = (const float*)d_in[1];
  const float* feat_st = (const float*)d_in[2];
  const float* Dv      = (const float*)d_in[3];
  const float* muv     = (const float*)d_in[4];
  const float* cv      = (const float*)d_in[5];
  const int*   adj4    = (const int*)d_in[6];
  const int*   adj25   = (const int*)d_in[7];
  const float* Wt0 = (const float*)d_in[8];
  const float* bt0 = (const float*)d_in[9];
  const float* Wt1 = (const float*)d_in[10];
  const float* bt1 = (const float*)d_in[11];
  const float* Wt2 = (const float*)d_in[12];
  const float* bt2 = (const float*)d_in[13];
  const float* Wq0 = (const float*)d_in[14];
  const float* bq0 = (const float*)d_in[15];
  const float* Wq1 = (const float*)d_in[16];
  const float* bq1 = (const float*)d_in[17];
  const float* Wq2 = (const float*)d_in[18];
  const float* bq2 = (const float*)d_in[19];
  const float* Wd0 = (const float*)d_in[20];
  const float* bd0 = (const float*)d_in[21];
  const float* Wd1 = (const float*)d_in[22];
  const float* bd1 = (const float*)d_in[23];
  const float* Wd2 = (const float*)d_in[24];
  const float* bd2 = (const float*)d_in[25];
  const float* Wd3 = (const float*)d_in[26];
  const float* bd3 = (const float*)d_in[27];

  float* ws  = (float*)d_ws;
  int*   wsi = (int*)(ws + O_FLTEND);
  float* out = (float*)d_out;
  const int use_stage = (ws_size >= WS_NEED) ? 1 : 0;
  float* stg = ws + O_STG;
  float* actb = ws + O_ACT;

  k_setup_small<<<1, 256, 0, stream>>>(Dv, muv, cv, ws);
  k_xpose<<<16, 256, 0, stream>>>(Wt0, Wq0, Wt1, Wq1, Wt2, Wq2, Wd0, Wd1, Wd2, Wd3,
                                  bt1, bq1, bt2, bq2, bd1, bd2, bd3, ws);
  k_setup_node<<<BN/4, 256, 0, stream>>>(phi, feat_dy, feat_st, adj4, adj25,
                                         Wt0, bt0, Wq0, bq0, Wd0, bd0, ws, wsi);
  k_build_rev<<<(BN*25 + 255)/256, 256, 0, stream>>>(adj25, wsi);

  float* fa = ws + O_FEATA; float* fb = ws + O_FEATB;
  float2* pa = (float2*)(ws + O_AXY2A);
  float2* pb = (float2*)(ws + O_AXY2B);
  for (int t = 0; t < TS; t++) {
    k_gather<<<BN/8, 512, 0, stream>>>(ws, wsi, wsi + BN, fa, pa, adj4, adj25, actb);
    k_mlp<<<BN/32, 512, 0, stream>>>(ws, actb, t, fa, fb, pb, stg, use_stage, out);
    float* tf = fa; fa = fb; fb = tf;
    float2* tp = pa; pa = pb; pb = tp;
  }
  if (use_stage) {
    const size_t tot = (size_t)BN*12*TS;
    k_out<<<(unsigned)((tot + 255)/256), 256, 0, stream>>>(stg, out);
  }
}

// Round 10
// 1236.698 us; speedup vs baseline: 1.1926x; 1.1926x over previous
//
#include <hip/hip_runtime.h>
#include <hip/hip_fp16.h>
#include <math.h>

// ============================================================================
// ConflictNet: 30-step graph-PDE scan, B=2, N=8000, DY=12.
// Round 17: RESTORE the verified best (R12, 1241us, absmax 0.25).
// R16's 1-pass x 4-node k_mlp regressed 19%: 4-node live state (~20 regs over
// long ranges) broke the <=128-VGPR budget that 2-blocks/CU LDS occupancy
// demands (same cliff as R9/R11, entered from the register side).
// R12 structure: split k_gather (1 node/wave, no LDS, one-round coalesced
// index loads + shfl redistribution, 8B packed {f, half2(ax,ay)} u_rig
// payload) + k_mlp (LDS weight pack, 8 waves, 2 passes x 2 nodes, fp32).
// Constraint log: fp16 MLP numerically dead (scan amplifies ~100x);
// occupancy attributes (launch_bounds(512,N)/waves_per_eu) force 64-VGPR
// spill; fusion loses to the split at this occupancy.
// ============================================================================

namespace {
constexpr int NB = 2;
constexpr int NN = 8000;
constexpr int BN = NB * NN;   // 16000
constexpr int TS = 30;
constexpr int CAP = 64;

// ---- packed weight layout (ws staging area and LDS) ----
constexpr int P_T0 = 0;        // [6][64][4]  Wt0 rows 0-23   (1536)
constexpr int P_Q0 = 1536;     // [6][64][4]  Wq0 rows 0-23   (1536)
constexpr int P_W1 = 3072;     // [16][64][4] Wt1|Wq1 fused   (4096)
constexpr int P_Q2 = 7168;     // [8][12][4]  Wq2             (384)
constexpr int P_Z  = 7552;     // [32]        Wt2[:,25]       (32)
constexpr int P_D0 = 7584;     // [3][32][4]  Wd0 rows 0-11   (384)
constexpr int P_D1 = 7968;     // [8][32][4]  Wd1             (1024)
constexpr int P_D2 = 8992;     // [8][64][4]  Wd2             (2048)
constexpr int P_D3 = 11040;    // [64]        Wd3             (64)
constexpr int P_BT1 = 11104;   // [32] bt1
constexpr int P_BQ1 = 11136;   // [32] bq1
constexpr int P_BQ2 = 11168;   // [16] bq2 (12 used)
constexpr int P_BD1 = 11184;   // [32] bd1
constexpr int P_BD2 = 11216;   // [64] bd2
constexpr int P_MISC= 11280;   // [0]=bd3[0], [1]=bt2[25]
constexpr int PACK_N = 11296;  // 45.2 KB

// ---- per-node activation slot in LDS (floats) ----
constexpr int A_AG = 0;
constexpr int A_NV = 0;
constexpr int A_H1 = 24;
constexpr int A_D1 = 24;
constexpr int A_D2 = 56;
constexpr int A_H2 = 152;
constexpr int A_SLOT = 216;    // 864 B

// ---- workspace float offsets ----
constexpr int O_COEFF = 0;                 // 144
constexpr int O_CFT   = 144;               // 144
constexpr int O_DIJ   = 288;               // 12
constexpr int O_MUIJ  = 300;               // 12
constexpr int O_MC    = 312;               // 12
constexpr int O_PACK  = 336;               // PACK_N
constexpr int O_GPX   = O_PACK + PACK_N + 16;  // BN
constexpr int O_GPY   = O_GPX + BN;
constexpr int O_H1T   = O_GPY + BN;        // BN*64
constexpr int O_H1Q   = O_H1T + BN*64;     // BN*64
constexpr int O_H1D   = O_H1Q + BN*64;     // BN*32
constexpr int O_FEATA = O_H1D + BN*32;     // BN*12
constexpr int O_FEATB = O_FEATA + BN*12;
constexpr int O_AXY2A = O_FEATB + BN*12;   // BN*12 float2 = BN*24 floats
constexpr int O_AXY2B = O_AXY2A + BN*24;
constexpr int O_ACT   = O_AXY2B + BN*24;   // [BN][48]: 0-11 agw, 12-23 udiff, 24-35 urig
constexpr int O_FLTEND= O_ACT + BN*48;
// int region: rev counts [BN], rev entries [BN*CAP]
constexpr int O_STG   = O_FLTEND + BN + BN*CAP;   // q0 staging [TS][BN*12]
constexpr int STG_N = TS*BN*12;
constexpr size_t WS_NEED = (size_t)(O_STG + STG_N) * 4;

// ---- output flat offsets ----
constexpr int OUS  = 0;
constexpr int OMIX = BN*TS;
constexpr int OQ0  = 2*BN*TS;
constexpr int OFD  = OQ0 + BN*12*TS;
}

__device__ __forceinline__ float group5_sum(float v, int lane) {
  int g = lane / 12, c = lane % 12;
  float s1 = __shfl(v, c + 12*((g+1)%5));
  float s2 = __shfl(v, c + 12*((g+2)%5));
  float s3 = __shfl(v, c + 12*((g+3)%5));
  float s4 = __shfl(v, c + 12*((g+4)%5));
  return v + s1 + s2 + s3 + s4;
}

__device__ __forceinline__ float pack_axy(float a, float b) {
  union { __half2 h2; float f; } cv;
  cv.h2 = __floats2half2_rn(a, b);
  return cv.f;
}
__device__ __forceinline__ void unpack_axy(float p, float& a, float& b) {
  union { float f; __half2 h2; } cv;
  cv.f = p;
  a = __low2float(cv.h2);
  b = __high2float(cv.h2);
}

// ---------------------------------------------------------------------------
__global__ void k_setup_small(const float* __restrict__ D, const float* __restrict__ mu,
                              const float* __restrict__ cv, float* ws) {
  int t = threadIdx.x;
  for (int e = t; e < 144; e += 256) {
    int r = e / 12, q = e % 12;
    int rb = r >> 2, cb = q >> 2, ri = r & 3, qi = q & 3;
    float val = 0.f;
    if (rb == cb) {
      int f = ri*4 + qi;
      if (f % 5 == 0) val = 1.f;
      else val = cv[64 + rb*12 + (f/5)*4 + (f%5) - 1];
    } else if (rb == 0 && cb == 2) val = cv[     ri*4 + qi];
    else if   (rb == 1 && cb == 2) val = cv[16 + ri*4 + qi];
    else if   (rb == 2 && cb == 0) val = cv[32 + ri*4 + qi];
    else if   (rb == 2 && cb == 1) val = cv[48 + ri*4 + qi];
    ws[O_COEFF + e] = fmaxf(val, 0.f);
  }
  if (t < 12) {
    ws[O_DIJ + t]  = (t < 4) ? 0.f : fmaxf(D[t-4], 0.f);
    ws[O_MUIJ + t] = (t < 4) ? fmaxf(mu[t], 0.f) : ((t < 8) ? 0.f : fmaxf(mu[t-4], 0.f));
  }
  __syncthreads();
  if (t < 144) {
    int r = t / 12, c = t % 12;
    ws[O_CFT + c*12 + r] = ws[O_COEFF + t];
  }
  if (t < 12) {
    float acc = 0.f;
    for (int c = 0; c < 12; c++) acc += ws[O_MUIJ + c] * ws[O_COEFF + c*12 + t];
    ws[O_MC + t] = acc;
  }
}

// ---------------------------------------------------------------------------
__global__ void k_xpose(const float* __restrict__ Wt0, const float* __restrict__ Wq0,
                        const float* __restrict__ Wt1, const float* __restrict__ Wq1,
                        const float* __restrict__ Wt2, const float* __restrict__ Wq2,
                        const float* __restrict__ Wd0, const float* __restrict__ Wd1,
                        const float* __restrict__ Wd2, const float* __restrict__ Wd3,
                        const float* __restrict__ bt1, const float* __restrict__ bq1,
                        const float* __restrict__ bt2, const float* __restrict__ bq2,
                        const float* __restrict__ bd1, const float* __restrict__ bd2,
                        const float* __restrict__ bd3,
                        float* ws) {
  const int t = blockIdx.x * blockDim.x + threadIdx.x;
  const int G = gridDim.x * blockDim.x;
  float* P = ws + O_PACK;
  for (int e = t; e < 1536; e += G) {
    int q = e / 256, r = e % 256, l = r / 4, j = r % 4;
    P[P_T0 + e] = Wt0[(4*q+j)*64 + l];
    P[P_Q0 + e] = Wq0[(4*q+j)*64 + l];
  }
  for (int e = t; e < 4096; e += G) {
    int q = e / 256, r = e % 256, l = r / 4, j = r % 4;
    P[P_W1 + e] = (l < 32) ? Wt1[(4*q+j)*32 + l] : Wq1[(4*q+j)*32 + (l-32)];
  }
  for (int e = t; e < 384; e += G) {
    int q = e / 48, r = e % 48, c = r / 4, j = r % 4;
    P[P_Q2 + e] = Wq2[(4*q+j)*12 + c];
  }
  for (int e = t; e < 32; e += G) P[P_Z + e] = Wt2[e*26 + 25];
  for (int e = t; e < 384; e += G) {
    int q = e / 128, r = e % 128, l = r / 4, j = r % 4;
    P[P_D0 + e] = Wd0[(4*q+j)*32 + l];
  }
  for (int e = t; e < 1024; e += G) {
    int q = e / 128, r = e % 128, l = r / 4, j = r % 4;
    P[P_D1 + e] = Wd1[(4*q+j)*32 + l];
  }
  for (int e = t; e < 2048; e += G) {
    int q = e / 256, r = e % 256, l = r / 4, j = r % 4;
    P[P_D2 + e] = Wd2[(4*q+j)*64 + l];
  }
  for (int e = t; e < 64; e += G) P[P_D3 + e] = Wd3[e];
  for (int e = t; e < 32; e += G) {
    P[P_BT1 + e] = bt1[e];
    P[P_BQ1 + e] = bq1[e];
    P[P_BD1 + e] = bd1[e];
  }
  for (int e = t; e < 12; e += G) P[P_BQ2 + e] = bq2[e];
  for (int e = t; e < 64; e += G) P[P_BD2 + e] = bd2[e];
  if (t == 0) { P[P_MISC + 0] = bd3[0]; P[P_MISC + 1] = bt2[25]; }
}

// ---------------------------------------------------------------------------
__global__ __launch_bounds__(256) void k_setup_node(
    const float* __restrict__ phi, const float* __restrict__ feat_dy,
    const float* __restrict__ feat_st,
    const int* __restrict__ adj4, const int* __restrict__ adj25,
    const float* __restrict__ Wt0, const float* __restrict__ bt0,
    const float* __restrict__ Wq0, const float* __restrict__ bq0,
    const float* __restrict__ Wd0, const float* __restrict__ bd0,
    float* ws, int* wsi) {
  const int wid  = (blockIdx.x * blockDim.x + threadIdx.x) >> 6;
  const int lane = threadIdx.x & 63;
  if (wid >= BN) return;
  const int b = wid / NN, n = wid % NN;

  const int* a4 = adj4 + n*4;
  const float gpx = phi[b*NN + a4[1]] - phi[b*NN + a4[0]];
  const float gpy = phi[b*NN + a4[3]] - phi[b*NN + a4[2]];
  if (lane == 0) { ws[O_GPX + wid] = gpx; ws[O_GPY + wid] = gpy; wsi[wid] = 0; }

  int idx = 0; float w = 0.f;
  if (lane < 25) { idx = adj25[n*25 + lane]; w = (lane == 0) ? 1.f : 0.01f; }
  float phiw = (lane < 25) ? w * phi[b*NN + idx] : 0.f;
  #pragma unroll
  for (int s = 32; s > 0; s >>= 1) phiw += __shfl_xor(phiw, s);

  float stv[6], stw[6];
  #pragma unroll
  for (int j = 0; j < 6; j++) {
    float x = (lane < 25) ? w * feat_st[(b*NN + idx)*6 + j] : 0.f;
    #pragma unroll
    for (int s = 32; s > 0; s >>= 1) x += __shfl_xor(x, s);
    stw[j] = x;
    stv[j] = feat_st[(b*NN + n)*6 + j];
  }
  const float phiv = phi[b*NN + n];

  float hT = bt0[lane] + phiv*Wt0[24*64 + lane] + phiw*Wt0[25*64 + lane];
  float hQ = bq0[lane] + phiv*Wq0[24*64 + lane] + phiw*Wq0[25*64 + lane];
  #pragma unroll
  for (int i = 0; i < 12; i++) {
    hT = fmaf(ws[O_DIJ  + i], Wt0[(26+i)*64 + lane], hT);
    hT = fmaf(ws[O_MUIJ + i], Wt0[(38+i)*64 + lane], hT);
  }
  #pragma unroll
  for (int j = 0; j < 6; j++) {
    hT = fmaf(stv[j], Wt0[(50+j)*64 + lane], hT);
    hT = fmaf(stw[j], Wt0[(56+j)*64 + lane], hT);
    hQ = fmaf(stv[j], Wq0[(26+j)*64 + lane], hQ);
    hQ = fmaf(stw[j], Wq0[(32+j)*64 + lane], hQ);
  }
  ws[O_H1T + wid*64 + lane] = hT;
  ws[O_H1Q + wid*64 + lane] = hQ;
  if (lane < 32) {
    float hD = bd0[lane];
    #pragma unroll
    for (int j = 0; j < 6; j++) hD = fmaf(stv[j], Wd0[(12+j)*32 + lane], hD);
    ws[O_H1D + wid*32 + lane] = hD;
  }
  if (lane < 12) {
    float f = feat_dy[wid*12 + lane];
    ws[O_FEATA + wid*12 + lane] = f;
    float mass = (f == 0.f) ? 1.f : f;
    float mc = ws[O_MC + lane];
    float axv = fminf(fmaxf(gpx*mc/mass, -2.f), 2.f);
    float ayv = fminf(fmaxf(gpy*mc/mass, -2.f), 2.f);
    float2* a2a = (float2*)(ws + O_AXY2A);
    a2a[wid*12 + lane] = make_float2(f, pack_axy(axv, ayv));
  }
}

// ---------------------------------------------------------------------------
__global__ void k_build_rev(const int* __restrict__ adj25, int* wsi) {
  int i = blockIdx.x * blockDim.x + threadIdx.x;
  if (i >= BN * 25) return;
  int b = i / (NN * 25);
  int rem = i % (NN * 25);
  int m = rem / 25, k = rem % 25;
  int tgt = adj25[i];
  int slot = atomicAdd(&wsi[b*NN + tgt], 1);
  if (slot < CAP) wsi[BN + (b*NN + tgt)*CAP + slot] = (m << 5) | k;
}

// ---------------------------------------------------------------------------
// Gather kernel: one node per wave, no LDS. All index data (adj25, all 64 rev
// entries) pulled with single coalesced loads and redistributed by __shfl, so
// every global gather issues in one round with no dependent load->load chains.
// u_rig reads the 8B packed {f, half2(ax,ay)} payload.
// ---------------------------------------------------------------------------
__global__ __launch_bounds__(512) void k_gather(
    const float* __restrict__ ws,
    const int* __restrict__ rcnt, const int* __restrict__ rent,
    const float* __restrict__ fsrc, const float2* __restrict__ a2src,
    const int* __restrict__ adj4, const int* __restrict__ adj25,
    float* __restrict__ actb) {
  const int wid_raw = (int)((blockIdx.x * blockDim.x + threadIdx.x) >> 6);
  if (wid_raw >= BN) return;
  const int wid  = __builtin_amdgcn_readfirstlane(wid_raw);  // wave-uniform
  const int lane = threadIdx.x & 63;
  const int c12  = lane % 12;
  const int g    = lane / 12;
  const int b = wid / NN, n = wid % NN;

  const int* a4p = adj4 + n*4;                       // uniform -> s_load
  const int m0 = a4p[0], m1 = a4p[1], m2 = a4p[2], m3 = a4p[3];
  int cnt = rcnt[wid]; if (cnt > CAP) cnt = CAP;     // uniform -> s_load
  const int idxv = (lane < 25) ? adj25[n*25 + lane] : 0;
  const int pkv  = rent[wid*CAP + lane];
  const float f_c  = fsrc[wid*12 + c12];
  const float dij  = ws[O_DIJ  + c12];
  const float muij = ws[O_MUIJ + c12];
  const float4* CFTp = (const float4*)(ws + O_CFT + c12*12);
  const float4 cf0 = CFTp[0], cf1 = CFTp[1], cf2 = CFTp[2];

  float agw = 0.f;
  {
    const int i0 = __shfl(idxv, g);
    const int i1 = __shfl(idxv, g + 5);
    const int i2 = __shfl(idxv, g + 10);
    const int i3 = __shfl(idxv, g + 15);
    const int i4 = __shfl(idxv, g + 20);
    if (g < 5) {
      const float v0 = fsrc[(b*NN + i0)*12 + c12];
      const float v1 = fsrc[(b*NN + i1)*12 + c12];
      const float v2 = fsrc[(b*NN + i2)*12 + c12];
      const float v3 = fsrc[(b*NN + i3)*12 + c12];
      const float v4 = fsrc[(b*NN + i4)*12 + c12];
      const float w0 = (g == 0) ? 1.f : 0.01f;
      agw = fmaf(w0,    v0, agw);
      agw = fmaf(0.01f, v1, agw);
      agw = fmaf(0.01f, v2, agw);
      agw = fmaf(0.01f, v3, agw);
      agw = fmaf(0.01f, v4, agw);
    }
    agw = group5_sum(agw, lane);
  }

  float udiff;
  {
    const float f0 = fsrc[(b*NN+m0)*12 + c12];
    const float f1 = fsrc[(b*NN+m1)*12 + c12];
    const float f2 = fsrc[(b*NN+m2)*12 + c12];
    const float f3 = fsrc[(b*NN+m3)*12 + c12];
    const float gx0 = ws[O_GPX + b*NN + m0], gx1 = ws[O_GPX + b*NN + m1];
    const float gy2 = ws[O_GPY + b*NN + m2], gy3 = ws[O_GPY + b*NN + m3];
    const float J = 4.f * ((f0+f1+f2+f3) - 4.f*f_c);
    const float Fdiv = gx1*f1 - gx0*f0 + gy3*f3 - gy2*f2;
    const float v = dij*J - muij*Fdiv;
    float acc;
    acc  = __shfl(v, 0) * cf0.x;
    acc  = fmaf(__shfl(v, 1), cf0.y, acc);
    acc  = fmaf(__shfl(v, 2), cf0.z, acc);
    acc  = fmaf(__shfl(v, 3), cf0.w, acc);
    acc  = fmaf(__shfl(v, 4), cf1.x, acc);
    acc  = fmaf(__shfl(v, 5), cf1.y, acc);
    acc  = fmaf(__shfl(v, 6), cf1.z, acc);
    acc  = fmaf(__shfl(v, 7), cf1.w, acc);
    acc  = fmaf(__shfl(v, 8), cf2.x, acc);
    acc  = fmaf(__shfl(v, 9), cf2.y, acc);
    acc  = fmaf(__shfl(v,10), cf2.z, acc);
    acc  = fmaf(__shfl(v,11), cf2.w, acc);
    udiff = acc;
  }

  float urig;
  {
    float usc = 0.f;
    #pragma unroll
    for (int it = 0; it < 8; ++it) {
      const int e = g + 5*it;
      const bool val = (g < 5) && (e < cnt);
      const int pk = __shfl(pkv, e & 63);
      const int m = pk >> 5, k = pk & 31;
      const int off = val ? ((b*NN + m)*12 + c12) : (wid*12 + c12);
      const float2 sm = a2src[off];
      float ax, ay; unpack_axy(sm.y, ax, ay);
      const float kx = (float)(k - (k/5)*5);
      const float ky = (float)(k/5);
      const float px = fmaxf(1.f - fabsf(ax - kx), 0.f);
      const float py = fmaxf(1.f - fabsf(ay - ky), 0.f);
      usc = fmaf(val ? px*py : 0.f, sm.x, usc);
    }
    if (cnt > 40) {            // uniform branch, ~0.2% of nodes
      #pragma unroll
      for (int it = 8; it < 13; ++it) {
        const int e = g + 5*it;
        const bool val = (g < 5) && (e < cnt);
        const int pk = __shfl(pkv, e & 63);
        const int m = pk >> 5, k = pk & 31;
        const int off = val ? ((b*NN + m)*12 + c12) : (wid*12 + c12);
        const float2 sm = a2src[off];
        float ax, ay; unpack_axy(sm.y, ax, ay);
        const float kx = (float)(k - (k/5)*5);
        const float ky = (float)(k/5);
        const float px = fmaxf(1.f - fabsf(ax - kx), 0.f);
        const float py = fmaxf(1.f - fabsf(ay - ky), 0.f);
        usc = fmaf(val ? px*py : 0.f, sm.x, usc);
      }
    }
    usc = group5_sum(usc, lane);
    urig = usc - f_c;
  }

  const float ov = (lane < 12) ? agw : ((lane < 24) ? udiff : urig);
  if (lane < 36) actb[wid*48 + lane] = ov;
}

// ---------------------------------------------------------------------------
// MLP kernel: 512 threads = 8 waves; 2 passes/wave of a 2-node pair.
// ---------------------------------------------------------------------------
__global__ __launch_bounds__(512) void k_mlp(
    const float* __restrict__ ws, const float* __restrict__ actb, int t,
    const float* __restrict__ fsrc,
    float* __restrict__ fdst, float2* __restrict__ a2dst,
    float* __restrict__ stg, int use_stage,
    float* __restrict__ out) {
  __shared__ __attribute__((aligned(16))) float sh[PACK_N + 16*A_SLOT];
  const int tid = threadIdx.x;
  {
    const float4* wp = (const float4*)(ws + O_PACK);
    float4* sp = (float4*)sh;
    for (int e = tid; e < PACK_N/4; e += 512) sp[e] = wp[e];
  }
  __syncthreads();

  const int wv   = tid >> 6;
  const int wvq  = __builtin_amdgcn_readfirstlane(wv);  // uniform wave id
  const int lane = tid & 63;
  const int c12 = lane % 12;
  const int l32 = lane & 31;
  const bool isQ = lane >= 32;
  float* act0 = sh + PACK_N + (wvq*2 + 0)*A_SLOT;
  float* act1 = sh + PACK_N + (wvq*2 + 1)*A_SLOT;

  const float mcv = ws[O_MC + c12];

  #pragma unroll 1
  for (int pass = 0; pass < 2; pass++) {
    const int nb = (blockIdx.x*16 + pass*8 + wvq) * 2;  // uniform

    float f_c[2], udiff[2], urig[2];
    #pragma unroll
    for (int j = 0; j < 2; j++) {
      const int wid = nb + j;
      float* actj = j ? act1 : act0;
      f_c[j] = fsrc[wid*12 + c12];
      const float agv = actb[wid*48 + c12];
      udiff[j] = actb[wid*48 + 12 + c12];
      urig[j]  = actb[wid*48 + 24 + c12];
      if (lane < 24) actj[A_AG + lane] = (lane < 12) ? f_c[j] : agv;
    }

    // ---- h1 ----
    {
      float h1t0 = ws[O_H1T + nb*64 + lane];
      float h1q0 = ws[O_H1Q + nb*64 + lane];
      float h1t1 = ws[O_H1T + (nb+1)*64 + lane];
      float h1q1 = ws[O_H1Q + (nb+1)*64 + lane];
      #pragma unroll
      for (int q = 0; q < 6; q++) {
        const float4 wt = *(const float4*)&sh[P_T0 + q*256 + lane*4];
        const float4 wq = *(const float4*)&sh[P_Q0 + q*256 + lane*4];
        const float4 a0 = *(const float4*)&act0[A_AG + 4*q];
        const float4 a1 = *(const float4*)&act1[A_AG + 4*q];
        h1t0 = fmaf(a0.x, wt.x, h1t0); h1q0 = fmaf(a0.x, wq.x, h1q0);
        h1t0 = fmaf(a0.y, wt.y, h1t0); h1q0 = fmaf(a0.y, wq.y, h1q0);
        h1t0 = fmaf(a0.z, wt.z, h1t0); h1q0 = fmaf(a0.z, wq.z, h1q0);
        h1t0 = fmaf(a0.w, wt.w, h1t0); h1q0 = fmaf(a0.w, wq.w, h1q0);
        h1t1 = fmaf(a1.x, wt.x, h1t1); h1q1 = fmaf(a1.x, wq.x, h1q1);
        h1t1 = fmaf(a1.y, wt.y, h1t1); h1q1 = fmaf(a1.y, wq.y, h1q1);
        h1t1 = fmaf(a1.z, wt.z, h1t1); h1q1 = fmaf(a1.z, wq.z, h1q1);
        h1t1 = fmaf(a1.w, wt.w, h1t1); h1q1 = fmaf(a1.w, wq.w, h1q1);
      }
      act0[A_H1 + lane]      = fmaxf(h1t0, 0.f);
      act0[A_H1 + 64 + lane] = fmaxf(h1q0, 0.f);
      act1[A_H1 + lane]      = fmaxf(h1t1, 0.f);
      act1[A_H1 + 64 + lane] = fmaxf(h1q1, 0.f);
    }

    // ---- h2 ----
    {
      const int hoff = isQ ? 64 : 0;
      float h2_0 = isQ ? sh[P_BQ1 + l32] : sh[P_BT1 + l32];
      float h2_1 = h2_0;
      #pragma unroll
      for (int q = 0; q < 16; q++) {
        const float4 w  = *(const float4*)&sh[P_W1 + q*256 + lane*4];
        const float4 a0 = *(const float4*)&act0[A_H1 + hoff + 4*q];
        const float4 a1 = *(const float4*)&act1[A_H1 + hoff + 4*q];
        h2_0 = fmaf(a0.x, w.x, h2_0); h2_1 = fmaf(a1.x, w.x, h2_1);
        h2_0 = fmaf(a0.y, w.y, h2_0); h2_1 = fmaf(a1.y, w.y, h2_1);
        h2_0 = fmaf(a0.z, w.z, h2_0); h2_1 = fmaf(a1.z, w.z, h2_1);
        h2_0 = fmaf(a0.w, w.w, h2_0); h2_1 = fmaf(a1.w, w.w, h2_1);
      }
      act0[A_H2 + lane] = fmaxf(h2_0, 0.f);
      act1[A_H2 + lane] = fmaxf(h2_1, 0.f);
    }

    // ---- mix + q0 ----
    float mix[2], q0v[2];
    {
      float mz0 = sh[P_MISC + 1], mz1 = mz0;
      float q00 = sh[P_BQ2 + c12], q01 = q00;
      #pragma unroll
      for (int q = 0; q < 8; q++) {
        const float4 wz  = *(const float4*)&sh[P_Z + 4*q];
        const float4 wq  = *(const float4*)&sh[P_Q2 + q*48 + c12*4];
        const float4 at0 = *(const float4*)&act0[A_H2 + 4*q];
        const float4 aq0 = *(const float4*)&act0[A_H2 + 32 + 4*q];
        const float4 at1 = *(const float4*)&act1[A_H2 + 4*q];
        const float4 aq1 = *(const float4*)&act1[A_H2 + 32 + 4*q];
        mz0 = fmaf(at0.x, wz.x, mz0); q00 = fmaf(aq0.x, wq.x, q00);
        mz0 = fmaf(at0.y, wz.y, mz0); q00 = fmaf(aq0.y, wq.y, q00);
        mz0 = fmaf(at0.z, wz.z, mz0); q00 = fmaf(aq0.z, wq.z, q00);
        mz0 = fmaf(at0.w, wz.w, mz0); q00 = fmaf(aq0.w, wq.w, q00);
        mz1 = fmaf(at1.x, wz.x, mz1); q01 = fmaf(aq1.x, wq.x, q01);
        mz1 = fmaf(at1.y, wz.y, mz1); q01 = fmaf(aq1.y, wq.y, q01);
        mz1 = fmaf(at1.z, wz.z, mz1); q01 = fmaf(aq1.z, wq.z, q01);
        mz1 = fmaf(at1.w, wz.w, mz1); q01 = fmaf(aq1.w, wq.w, q01);
      }
      mix[0] = 1.f / (1.f + expf(-mz0));
      mix[1] = 1.f / (1.f + expf(-mz1));
      q0v[0] = q00; q0v[1] = q01;
    }

    // ---- update + outputs + next {f, packed ax/ay} ----
    #pragma unroll
    for (int j = 0; j < 2; j++) {
      const int wid = nb + j;
      float* actj = j ? act1 : act0;
      const float newv = f_c[j] + mix[j]*udiff[j] + (1.f - mix[j])*urig[j] + q0v[j];
      if (lane < 12) {
        actj[A_NV + lane] = newv;
        if (use_stage) stg[(size_t)t*BN*12 + wid*12 + lane] = q0v[j];
        else           out[OQ0 + (wid*12 + lane)*TS + t] = q0v[j];
        out[OFD + (wid*TS + t)*12 + lane] = newv;
        fdst[wid*12 + lane] = newv;
        float mass = (newv == 0.f) ? 1.f : newv;
        float gpxn = ws[O_GPX + wid], gpyn = ws[O_GPY + wid];
        float axn = fminf(fmaxf(gpxn*mcv/mass, -2.f), 2.f);
        float ayn = fminf(fmaxf(gpyn*mcv/mass, -2.f), 2.f);
        a2dst[wid*12 + lane] = make_float2(newv, pack_axy(axn, ayn));
      }
      if (lane == 0) out[OMIX + wid*TS + t] = mix[j];
    }

    // ---- dec ----
    {
      float d1_0 = ws[O_H1D + nb*32 + l32];
      float d1_1 = ws[O_H1D + (nb+1)*32 + l32];
      #pragma unroll
      for (int q = 0; q < 3; q++) {
        const float4 w  = *(const float4*)&sh[P_D0 + q*128 + l32*4];
        const float4 a0 = *(const float4*)&act0[A_NV + 4*q];
        const float4 a1 = *(const float4*)&act1[A_NV + 4*q];
        d1_0 = fmaf(a0.x, w.x, d1_0); d1_1 = fmaf(a1.x, w.x, d1_1);
        d1_0 = fmaf(a0.y, w.y, d1_0); d1_1 = fmaf(a1.y, w.y, d1_1);
        d1_0 = fmaf(a0.z, w.z, d1_0); d1_1 = fmaf(a1.z, w.z, d1_1);
        d1_0 = fmaf(a0.w, w.w, d1_0); d1_1 = fmaf(a1.w, w.w, d1_1);
      }
      if (lane < 32) {
        act0[A_D1 + lane] = fmaxf(d1_0, 0.f);
        act1[A_D1 + lane] = fmaxf(d1_1, 0.f);
      }
    }
    {
      float d2_0 = sh[P_BD1 + l32], d2_1 = d2_0;
      #pragma unroll
      for (int q = 0; q < 8; q++) {
        const float4 w  = *(const float4*)&sh[P_D1 + q*128 + l32*4];
        const float4 a0 = *(const float4*)&act0[A_D1 + 4*q];
        const float4 a1 = *(const float4*)&act1[A_D1 + 4*q];
        d2_0 = fmaf(a0.x, w.x, d2_0); d2_1 = fmaf(a1.x, w.x, d2_1);
        d2_0 = fmaf(a0.y, w.y, d2_0); d2_1 = fmaf(a1.y, w.y, d2_1);
        d2_0 = fmaf(a0.z, w.z, d2_0); d2_1 = fmaf(a1.z, w.z, d2_1);
        d2_0 = fmaf(a0.w, w.w, d2_0); d2_1 = fmaf(a1.w, w.w, d2_1);
      }
      if (lane < 32) {
        act0[A_D2 + lane] = fmaxf(d2_0, 0.f);
        act1[A_D2 + lane] = fmaxf(d2_1, 0.f);
      }
    }
    {
      float d3_0 = sh[P_BD2 + lane], d3_1 = d3_0;
      #pragma unroll
      for (int q = 0; q < 8; q++) {
        const float4 w  = *(const float4*)&sh[P_D2 + q*256 + lane*4];
        const float4 a0 = *(const float4*)&act0[A_D2 + 4*q];
        const float4 a1 = *(const float4*)&act1[A_D2 + 4*q];
        d3_0 = fmaf(a0.x, w.x, d3_0); d3_1 = fmaf(a1.x, w.x, d3_1);
        d3_0 = fmaf(a0.y, w.y, d3_0); d3_1 = fmaf(a1.y, w.y, d3_1);
        d3_0 = fmaf(a0.z, w.z, d3_0); d3_1 = fmaf(a1.z, w.z, d3_1);
        d3_0 = fmaf(a0.w, w.w, d3_0); d3_1 = fmaf(a1.w, w.w, d3_1);
      }
      const float wd3 = sh[P_D3 + lane];
      float u0 = fmaxf(d3_0, 0.f) * wd3;
      float u1 = fmaxf(d3_1, 0.f) * wd3;
      #pragma unroll
      for (int s2 = 32; s2 > 0; s2 >>= 1) {
        u0 += __shfl_xor(u0, s2);
        u1 += __shfl_xor(u1, s2);
      }
      if (lane == 0) {
        const float b3 = sh[P_MISC + 0];
        out[OUS + nb*TS + t]     = u0 + b3;
        out[OUS + (nb+1)*TS + t] = u1 + b3;
      }
    }
  }
}

// ---------------------------------------------------------------------------
// Final reorder: staged step-major q0 -> (B,N,12,1,T) layout.
// ---------------------------------------------------------------------------
__global__ void k_out(const float* __restrict__ stg, float* __restrict__ out) {
  const size_t NQ = (size_t)BN*12*TS;
  size_t i = (size_t)blockIdx.x * blockDim.x + threadIdx.x;
  if (i < NQ) {
    int e = (int)(i / TS), t = (int)(i % TS);
    out[OQ0 + i] = stg[(size_t)t*BN*12 + e];
  }
}

// ---------------------------------------------------------------------------
extern "C" void kernel_launch(void* const* d_in, const int* in_sizes, int n_in,
                              void* d_out, int out_size, void* d_ws, size_t ws_size,
                              hipStream_t stream) {
  const float* phi     = (const float*)d_in[0];
  const float* feat_dy = (const float*)d_in[1];
  const float* feat_st = (const float*)d_in[2];
  const float* Dv      = (const float*)d_in[3];
  const float* muv     = (const float*)d_in[4];
  const float* cv      = (const float*)d_in[5];
  const int*   adj4    = (const int*)d_in[6];
  const int*   adj25   = (const int*)d_in[7];
  const float* Wt0 = (const float*)d_in[8];
  const float* bt0 = (const float*)d_in[9];
  const float* Wt1 = (const float*)d_in[10];
  const float* bt1 = (const float*)d_in[11];
  const float* Wt2 = (const float*)d_in[12];
  const float* bt2 = (const float*)d_in[13];
  const float* Wq0 = (const float*)d_in[14];
  const float* bq0 = (const float*)d_in[15];
  const float* Wq1 = (const float*)d_in[16];
  const float* bq1 = (const float*)d_in[17];
  const float* Wq2 = (const float*)d_in[18];
  const float* bq2 = (const float*)d_in[19];
  const float* Wd0 = (const float*)d_in[20];
  const float* bd0 = (const float*)d_in[21];
  const float* Wd1 = (const float*)d_in[22];
  const float* bd1 = (const float*)d_in[23];
  const float* Wd2 = (const float*)d_in[24];
  const float* bd2 = (const float*)d_in[25];
  const float* Wd3 = (const float*)d_in[26];
  const float* bd3 = (const float*)d_in[27];

  float* ws  = (float*)d_ws;
  int*   wsi = (int*)(ws + O_FLTEND);
  float* out = (float*)d_out;
  const int use_stage = (ws_size >= WS_NEED) ? 1 : 0;
  float* stg = ws + O_STG;
  float* actb = ws + O_ACT;

  k_setup_small<<<1, 256, 0, stream>>>(Dv, muv, cv, ws);
  k_xpose<<<16, 256, 0, stream>>>(Wt0, Wq0, Wt1, Wq1, Wt2, Wq2, Wd0, Wd1, Wd2, Wd3,
                                  bt1, bq1, bt2, bq2, bd1, bd2, bd3, ws);
  k_setup_node<<<BN/4, 256, 0, stream>>>(phi, feat_dy, feat_st, adj4, adj25,
                                         Wt0, bt0, Wq0, bq0, Wd0, bd0, ws, wsi);
  k_build_rev<<<(BN*25 + 255)/256, 256, 0, stream>>>(adj25, wsi);

  float* fa = ws + O_FEATA; float* fb = ws + O_FEATB;
  float2* pa = (float2*)(ws + O_AXY2A);
  float2* pb = (float2*)(ws + O_AXY2B);
  for (int t = 0; t < TS; t++) {
    k_gather<<<BN/8, 512, 0, stream>>>(ws, wsi, wsi + BN, fa, pa, adj4, adj25, actb);
    k_mlp<<<BN/32, 512, 0, stream>>>(ws, actb, t, fa, fb, pb, stg, use_stage, out);
    float* tf = fa; fa = fb; fb = tf;
    float2* tp = pa; pa = pb; pb = tp;
  }
  if (use_stage) {
    const size_t tot = (size_t)BN*12*TS;
    k_out<<<(unsigned)((tot + 255)/256), 256, 0, stream>>>(stg, out);
  }
}